// Round 1
// baseline (735.674 us; speedup 1.0000x reference)
//
#include <hip/hip_runtime.h>
#include <hip/hip_bf16.h>
#include <climits>
#include <math.h>

#define NN 200000
#define NE 600000
#define FD 128

// ws int layout
#define WS_CNT 0
#define WS_MIN1 16
#define WS_MIN2 (16 + NN)
#define WS_ACT  (16 + 2 * NN)

__global__ __launch_bounds__(256) void k_init(int* __restrict__ ws) {
    int i = blockIdx.x * 256 + threadIdx.x;
    if (i == 0) ws[WS_CNT] = 0;
    if (i < NN) { ws[WS_MIN1 + i] = INT_MAX; ws[WS_MIN2 + i] = INT_MAX; }
}

__global__ __launch_bounds__(256) void k_min1(const int* __restrict__ ei, int* __restrict__ ws) {
    int e = blockIdx.x * 256 + threadIdx.x;
    if (e >= NE) return;
    int s = ei[e], d = ei[NE + e];
    if (s != d) {
        atomicMin(&ws[WS_MIN1 + s], d);
        atomicMin(&ws[WS_MIN1 + d], s);
    }
}

__global__ __launch_bounds__(256) void k_min2(const int* __restrict__ ei, int* __restrict__ ws) {
    int e = blockIdx.x * 256 + threadIdx.x;
    if (e >= NE) return;
    int s = ei[e], d = ei[NE + e];
    if (s != d) {
        if (d != ws[WS_MIN1 + s]) atomicMin(&ws[WS_MIN2 + s], d);
        if (s != ws[WS_MIN1 + d]) atomicMin(&ws[WS_MIN2 + d], s);
    }
}

__global__ __launch_bounds__(256) void k_compact(const int* __restrict__ types, int* __restrict__ ws,
                                                 float* __restrict__ out) {
    int n = blockIdx.x * 256 + threadIdx.x;
    if (n >= NN) return;
    bool has_two = ws[WS_MIN2 + n] < NN;  // min2 real => min1 real too
    bool is_bif = (types[n] == 1);
    out[(size_t)NN * FD + n] = is_bif ? 0.5f : 0.0f;  // overwritten below for active nodes
    if (is_bif && has_two) {
        int pos = atomicAdd(&ws[WS_CNT], 1);
        ws[WS_ACT + pos] = n;
    }
}

__global__ __launch_bounds__(256) void k_copy(const float4* __restrict__ x, float4* __restrict__ out) {
    int i = blockIdx.x * 256 + threadIdx.x;  // grid sized exactly: NN*FD/4/256
    out[i] = x[i];
}

// MLP over active nodes, 16 nodes per block, 256 threads.
// smemA: ctxT[384][20] -> hT[256][20] -> procT[128][20] (stride 20 = 16B-aligned pad)
__global__ __launch_bounds__(256) void k_mlp(
    const float* __restrict__ x,
    const float* __restrict__ w1, const float* __restrict__ b1,
    const float* __restrict__ w2, const float* __restrict__ b2,
    const float* __restrict__ ln_g, const float* __restrict__ ln_b,
    const float* __restrict__ mw1, const float* __restrict__ mb1,
    const float* __restrict__ mw2, const float* __restrict__ mb2,
    const int* __restrict__ ws, float* __restrict__ out)
{
    __shared__ __align__(16) float smemA[384 * 20];   // 30720 B
    __shared__ __align__(16) float wpan[32 * 256];    // 32768 B
    __shared__ int nodes3[48];
    __shared__ float red[64];

    const int t = threadIdx.x;
    const int count = ws[WS_CNT];
    const int base = blockIdx.x * 16;
    if (base >= count) return;
    const int nvalid = min(16, count - base);

    if (t < 16) {
        int idx = min(base + t, count - 1);
        int node = ws[WS_ACT + idx];
        nodes3[t] = node;
        nodes3[16 + t] = ws[WS_MIN1 + node];
        nodes3[32 + t] = ws[WS_MIN2 + node];
    }
    __syncthreads();

    // Stage ctx^T: rows k=0..383 (self|n0|n1), cols n=0..15
    for (int i = t; i < 16 * 384; i += 256) {
        int n = i / 384;
        int k = i - n * 384;
        int src = nodes3[(k >> 7) * 16 + n];
        smemA[k * 20 + n] = x[src * FD + (k & 127)];
    }

    const int tn4 = (t & 3) * 4;  // node group: nodes tn4..tn4+3
    const int tc = t >> 2;        // 0..63

    // ---- GEMM1: h[16][256] = relu(ctx @ w1 + b1), cols 4*tc..4*tc+3 ----
    float acc[4][4] = {};
    for (int k0 = 0; k0 < 384; k0 += 32) {
        __syncthreads();
        for (int j = t; j < 2048; j += 256)
            ((float4*)wpan)[j] = ((const float4*)(w1 + k0 * 256))[j];
        __syncthreads();
        #pragma unroll
        for (int k = 0; k < 32; ++k) {
            float4 a = *(const float4*)&smemA[(k0 + k) * 20 + tn4];
            float4 b = *(const float4*)&wpan[k * 256 + tc * 4];
            acc[0][0] += a.x * b.x; acc[0][1] += a.x * b.y; acc[0][2] += a.x * b.z; acc[0][3] += a.x * b.w;
            acc[1][0] += a.y * b.x; acc[1][1] += a.y * b.y; acc[1][2] += a.y * b.z; acc[1][3] += a.y * b.w;
            acc[2][0] += a.z * b.x; acc[2][1] += a.z * b.y; acc[2][2] += a.z * b.z; acc[2][3] += a.z * b.w;
            acc[3][0] += a.w * b.x; acc[3][1] += a.w * b.y; acc[3][2] += a.w * b.z; acc[3][3] += a.w * b.w;
        }
    }
    __syncthreads();
    {
        float4 bb = *(const float4*)&b1[tc * 4];
        float bbv[4] = {bb.x, bb.y, bb.z, bb.w};
        #pragma unroll
        for (int j = 0; j < 4; ++j)
            #pragma unroll
            for (int i = 0; i < 4; ++i)
                smemA[(tc * 4 + j) * 20 + tn4 + i] = fmaxf(acc[i][j] + bbv[j], 0.0f);
    }
    __syncthreads();

    // ---- GEMM2: proc_pre[16][128] = h @ w2 + b2, cols 2*tc, 2*tc+1 ----
    float acc2[4][2] = {};
    for (int k0 = 0; k0 < 256; k0 += 64) {
        __syncthreads();
        for (int j = t; j < 2048; j += 256)
            ((float4*)wpan)[j] = ((const float4*)(w2 + k0 * 128))[j];
        __syncthreads();
        #pragma unroll
        for (int k = 0; k < 64; ++k) {
            float4 a = *(const float4*)&smemA[(k0 + k) * 20 + tn4];
            float2 b = *(const float2*)&wpan[k * 128 + tc * 2];
            acc2[0][0] += a.x * b.x; acc2[0][1] += a.x * b.y;
            acc2[1][0] += a.y * b.x; acc2[1][1] += a.y * b.y;
            acc2[2][0] += a.z * b.x; acc2[2][1] += a.z * b.y;
            acc2[3][0] += a.w * b.x; acc2[3][1] += a.w * b.y;
        }
    }
    __syncthreads();
    {
        float2 bb = *(const float2*)&b2[tc * 2];
        #pragma unroll
        for (int i = 0; i < 4; ++i) {
            smemA[(tc * 2 + 0) * 20 + tn4 + i] = acc2[i][0] + bb.x;
            smemA[(tc * 2 + 1) * 20 + tn4 + i] = acc2[i][1] + bb.y;
        }
    }
    __syncthreads();

    // ---- LayerNorm (per node over 128 cols) + write `updated` ----
    {
        const int n = t >> 4, j = t & 15;
        float s = 0.f, sq = 0.f;
        #pragma unroll
        for (int i = 0; i < 8; ++i) {
            float v = smemA[(j + 16 * i) * 20 + n];
            s += v; sq += v * v;
        }
        #pragma unroll
        for (int d = 1; d < 16; d <<= 1) {
            s  += __shfl_xor(s, d, 16);
            sq += __shfl_xor(sq, d, 16);
        }
        float mu = s * (1.f / 128.f);
        float rs = rsqrtf(sq * (1.f / 128.f) - mu * mu + 1e-5f);
        const bool wv = (n < nvalid);
        const int node = nodes3[n];
        #pragma unroll
        for (int i = 0; i < 8; ++i) {
            int c = j + 16 * i;
            float v = (smemA[c * 20 + n] - mu) * rs * ln_g[c] + ln_b[c];
            smemA[c * 20 + n] = v;
            if (wv) out[node * FD + c] = v;
        }
    }
    __syncthreads();

    // ---- Murray head: sigmoid(relu(proc @ mw1 + mb1) @ mw2 + mb2) ----
    for (int j = t; j < 2048; j += 256)
        ((float4*)wpan)[j] = ((const float4*)mw1)[j];
    __syncthreads();
    {
        float a3[4] = {};
        #pragma unroll 4
        for (int k = 0; k < 128; ++k) {
            float4 a = *(const float4*)&smemA[k * 20 + tn4];
            float b = wpan[k * 64 + tc];
            a3[0] += a.x * b; a3[1] += a.y * b; a3[2] += a.z * b; a3[3] += a.w * b;
        }
        float mb1v = mb1[tc];
        float mw2v = mw2[tc];
        float part[4];
        #pragma unroll
        for (int i = 0; i < 4; ++i) part[i] = fmaxf(a3[i] + mb1v, 0.f) * mw2v;
        #pragma unroll
        for (int d = 4; d < 64; d <<= 1)
            #pragma unroll
            for (int i = 0; i < 4; ++i) part[i] += __shfl_down(part[i], d, 64);
        if ((t & 63) < 4) {
            #pragma unroll
            for (int i = 0; i < 4; ++i)
                red[(t >> 6) * 16 + (t & 3) * 4 + i] = part[i];
        }
    }
    __syncthreads();
    if (t < 16) {
        float m = red[t] + red[16 + t] + red[32 + t] + red[48 + t] + mb2[0];
        if (t < nvalid) out[(size_t)NN * FD + nodes3[t]] = 1.f / (1.f + expf(-m));
    }
}

extern "C" void kernel_launch(void* const* d_in, const int* in_sizes, int n_in,
                              void* d_out, int out_size, void* d_ws, size_t ws_size,
                              hipStream_t stream) {
    const float* x   = (const float*)d_in[0];
    const int*   ei  = (const int*)d_in[1];
    const int* types = (const int*)d_in[2];
    const float* w1  = (const float*)d_in[3];
    const float* b1  = (const float*)d_in[4];
    const float* w2  = (const float*)d_in[5];
    const float* b2  = (const float*)d_in[6];
    const float* lg  = (const float*)d_in[7];
    const float* lb  = (const float*)d_in[8];
    const float* mw1 = (const float*)d_in[9];
    const float* mb1 = (const float*)d_in[10];
    const float* mw2 = (const float*)d_in[11];
    const float* mb2 = (const float*)d_in[12];
    float* out = (float*)d_out;
    int* ws = (int*)d_ws;

    k_init<<<(NN + 255) / 256, 256, 0, stream>>>(ws);
    k_min1<<<(NE + 255) / 256, 256, 0, stream>>>(ei, ws);
    k_min2<<<(NE + 255) / 256, 256, 0, stream>>>(ei, ws);
    k_compact<<<(NN + 255) / 256, 256, 0, stream>>>(types, ws, out);
    k_copy<<<(NN * FD / 4) / 256, 256, 0, stream>>>((const float4*)x, (float4*)out);
    k_mlp<<<(NN + 15) / 16, 256, 0, stream>>>(x, w1, b1, w2, b2, lg, lb, mw1, mb1, mw2, mb2, ws, out);
}

// Round 2
// 400.926 us; speedup vs baseline: 1.8349x; 1.8349x over previous
//
#include <hip/hip_runtime.h>
#include <hip/hip_bf16.h>
#include <climits>
#include <math.h>

#define NN 200000
#define NE 600000
#define FD 128

// ws int layout
#define WS_CNT 0
#define WS_MIN1 16
#define WS_MIN2 (16 + NN)
#define WS_ACT  (16 + 2 * NN)
// bf16 weight packs (byte offsets into ws); all 16B-aligned
#define WS_PACK_BYTES ((size_t)(16 + 3 * NN) * 4)        // 2400064
#define W1P_ELEMS (48 * 256 * 8)                          // 98304
#define W2P_ELEMS (32 * 128 * 8)                          // 32768
#define MW1P_ELEMS (16 * 64 * 8)                          // 8192

typedef __attribute__((ext_vector_type(8))) short short8;
typedef __attribute__((ext_vector_type(4))) float f32x4;

__device__ __forceinline__ unsigned short f2bf(float f) {
    __hip_bfloat16 h = __float2bfloat16(f);
    return *reinterpret_cast<unsigned short*>(&h);
}

__device__ __forceinline__ void gl_lds16(const void* gp, void* lp) {
    __builtin_amdgcn_global_load_lds(
        (const __attribute__((address_space(1))) void*)gp,
        (__attribute__((address_space(3))) void*)lp, 16, 0, 0);
}

__global__ __launch_bounds__(256) void k_init(int* __restrict__ ws) {
    int i = blockIdx.x * 256 + threadIdx.x;
    if (i == 0) ws[WS_CNT] = 0;
    if (i < NN) { ws[WS_MIN1 + i] = INT_MAX; ws[WS_MIN2 + i] = INT_MAX; }
}

__global__ __launch_bounds__(256) void k_min1(const int* __restrict__ ei, int* __restrict__ ws) {
    int e = blockIdx.x * 256 + threadIdx.x;
    if (e >= NE) return;
    int s = ei[e], d = ei[NE + e];
    if (s != d) {
        atomicMin(&ws[WS_MIN1 + s], d);
        atomicMin(&ws[WS_MIN1 + d], s);
    }
}

__global__ __launch_bounds__(256) void k_min2(const int* __restrict__ ei, int* __restrict__ ws) {
    int e = blockIdx.x * 256 + threadIdx.x;
    if (e >= NE) return;
    int s = ei[e], d = ei[NE + e];
    if (s != d) {
        if (d != ws[WS_MIN1 + s]) atomicMin(&ws[WS_MIN2 + s], d);
        if (s != ws[WS_MIN1 + d]) atomicMin(&ws[WS_MIN2 + d], s);
    }
}

__global__ __launch_bounds__(256) void k_compact(const int* __restrict__ types, int* __restrict__ ws,
                                                 float* __restrict__ out) {
    int n = blockIdx.x * 256 + threadIdx.x;
    if (n >= NN) return;
    bool has_two = ws[WS_MIN2 + n] < NN;
    bool is_bif = (types[n] == 1);
    out[(size_t)NN * FD + n] = is_bif ? 0.5f : 0.0f;
    if (is_bif && has_two) {
        int pos = atomicAdd(&ws[WS_CNT], 1);
        ws[WS_ACT + pos] = n;
    }
}

__global__ __launch_bounds__(256) void k_copy(const float4* __restrict__ x, float4* __restrict__ out) {
    int i = blockIdx.x * 256 + threadIdx.x;
    out[i] = x[i];
}

// Pack weights to bf16 in MFMA B-fragment order: [kc][n][8] with value w[kc*8+j][n].
__global__ __launch_bounds__(256) void k_pack(const float* __restrict__ w1, const float* __restrict__ w2,
                                              const float* __restrict__ mw1,
                                              unsigned short* __restrict__ w1p,
                                              unsigned short* __restrict__ w2p,
                                              unsigned short* __restrict__ mw1p) {
    int i = blockIdx.x * 256 + threadIdx.x;
    if (i < 12288) {                      // w1: 48 kc x 256 n
        int kc = i >> 8, n = i & 255;
        #pragma unroll
        for (int j = 0; j < 8; ++j) w1p[i * 8 + j] = f2bf(w1[(kc * 8 + j) * 256 + n]);
    } else if (i < 12288 + 4096) {        // w2: 32 kc x 128 n
        int ii = i - 12288;
        int kc = ii >> 7, n = ii & 127;
        #pragma unroll
        for (int j = 0; j < 8; ++j) w2p[ii * 8 + j] = f2bf(w2[(kc * 8 + j) * 128 + n]);
    } else if (i < 12288 + 4096 + 1024) { // mw1: 16 kc x 64 n
        int ii = i - 16384;
        int kc = ii >> 6, n = ii & 63;
        #pragma unroll
        for (int j = 0; j < 8; ++j) mw1p[ii * 8 + j] = f2bf(mw1[(kc * 8 + j) * 64 + n]);
    }
}

// ---- MFMA MLP: 64 active nodes / block, 256 threads (4 waves) ----
// LDS region A (bytes 0..50432): ctx A-frags [48kc][64m][8] bf16 (49152 B)
//   -> h A-frags [32kc][64m][8] bf16 (32768 B)
//   -> proc fp32 [64m][stride 133] (34048 B) + proc A-frags bf16 at 34048 (16384 B)
// LDS region B (16384 B): weight panel (contiguous copy of pack)
#define REGA_BYTES 50432
#define PF_BYTE 34048
__global__ __launch_bounds__(256, 2) void k_mlp(
    const float* __restrict__ x,
    const float* __restrict__ b1, const float* __restrict__ b2,
    const float* __restrict__ ln_g, const float* __restrict__ ln_b,
    const float* __restrict__ mb1, const float* __restrict__ mw2, const float* __restrict__ mb2,
    const unsigned short* __restrict__ w1p, const unsigned short* __restrict__ w2p,
    const unsigned short* __restrict__ mw1p,
    const int* __restrict__ ws, float* __restrict__ out)
{
    __shared__ __align__(16) char smem[REGA_BYTES + 16384];
    __shared__ int nodes3[192];
    __shared__ float red[256];

    unsigned short* s_a16 = (unsigned short*)smem;
    short8* s_a8 = (short8*)smem;
    float* s_cF = (float*)smem;
    char* s_b = smem + REGA_BYTES;
    short8* s_b8 = (short8*)s_b;

    const int t = threadIdx.x;
    const int wv = t >> 6;
    const int lane = t & 63;
    const int q = lane >> 4;
    const int l16 = lane & 15;

    const int count = ws[WS_CNT];
    const int base = blockIdx.x * 64;
    if (base >= count) return;
    const int nvalid = min(64, count - base);

    if (t < 64) {
        int idx = min(base + t, count - 1);
        int node = ws[WS_ACT + idx];
        nodes3[t] = node;
        nodes3[64 + t] = ws[WS_MIN1 + node];
        nodes3[128 + t] = ws[WS_MIN2 + node];
    }
    __syncthreads();

    // Stage ctx as bf16 A-fragments: [kc=seg*16+(c>>3)][m][8]
    for (int i = t; i < 64 * 96; i += 256) {
        int m = i / 96;
        int f4 = i - m * 96;
        int seg = f4 >> 5;
        int c = (f4 & 31) * 4;
        int src = nodes3[seg * 64 + m];
        const float4 v = *(const float4*)&x[(size_t)src * FD + c];
        int k = seg * FD + c;
        int kc = k >> 3, j0 = k & 7;
        ushort4 p;
        p.x = f2bf(v.x); p.y = f2bf(v.y); p.z = f2bf(v.z); p.w = f2bf(v.w);
        *(ushort4*)&s_a16[(kc * 64 + m) * 8 + j0] = p;
    }

    // ---- GEMM1: C[64][256] = ctx[64][384] @ w1 ; wave wv owns n in [wv*64, wv*64+64) ----
    const int wn = wv * 64;
    f32x4 acc[4][4];
    #pragma unroll
    for (int a = 0; a < 4; ++a)
        #pragma unroll
        for (int b = 0; b < 4; ++b) acc[a][b] = (f32x4){0.f, 0.f, 0.f, 0.f};

    for (int p = 0; p < 12; ++p) {
        __syncthreads();  // s_b free; (p==0) also: ctx staging done
        {
            const char* src = (const char*)(w1p) + p * 16384;
            #pragma unroll
            for (int it = 0; it < 4; ++it) {
                int chunk = it * 4 + wv;
                gl_lds16(src + chunk * 1024 + lane * 16, s_b + chunk * 1024);
            }
        }
        __syncthreads();
        short8 a[4], b[4];
        #pragma unroll
        for (int mt = 0; mt < 4; ++mt) a[mt] = s_a8[(p * 4 + q) * 64 + mt * 16 + l16];
        #pragma unroll
        for (int nt = 0; nt < 4; ++nt) b[nt] = s_b8[q * 256 + wn + nt * 16 + l16];
        #pragma unroll
        for (int mt = 0; mt < 4; ++mt)
            #pragma unroll
            for (int nt = 0; nt < 4; ++nt)
                acc[mt][nt] = __builtin_amdgcn_mfma_f32_16x16x32_bf16(a[mt], b[nt], acc[mt][nt], 0, 0, 0);
    }
    __syncthreads();  // all ctx reads done; reuse region A for h frags

    {
        float b1v[4];
        #pragma unroll
        for (int nt = 0; nt < 4; ++nt) b1v[nt] = b1[wn + nt * 16 + l16];
        #pragma unroll
        for (int mt = 0; mt < 4; ++mt)
            #pragma unroll
            for (int nt = 0; nt < 4; ++nt) {
                int n = wn + nt * 16 + l16;
                #pragma unroll
                for (int r = 0; r < 4; ++r) {
                    float v = fmaxf(acc[mt][nt][r] + b1v[nt], 0.f);
                    int m = mt * 16 + q * 4 + r;
                    s_a16[((n >> 3) * 64 + m) * 8 + (n & 7)] = f2bf(v);
                }
            }
    }

    // ---- GEMM2: C2[64][128] = h[64][256] @ w2 ; wave owns n in [wv*32, wv*32+32) ----
    const int wn2 = wv * 32;
    f32x4 acc2[4][2];
    #pragma unroll
    for (int a = 0; a < 4; ++a)
        #pragma unroll
        for (int b = 0; b < 2; ++b) acc2[a][b] = (f32x4){0.f, 0.f, 0.f, 0.f};

    for (int p = 0; p < 4; ++p) {
        __syncthreads();  // (p==0) h-frag writes done; s_b free
        {
            const char* src = (const char*)(w2p) + p * 16384;
            #pragma unroll
            for (int it = 0; it < 4; ++it) {
                int chunk = it * 4 + wv;
                gl_lds16(src + chunk * 1024 + lane * 16, s_b + chunk * 1024);
            }
        }
        __syncthreads();
        #pragma unroll
        for (int ks = 0; ks < 2; ++ks) {
            int kcp = ks * 4 + q;
            short8 a[4], b[2];
            #pragma unroll
            for (int mt = 0; mt < 4; ++mt) a[mt] = s_a8[(p * 8 + kcp) * 64 + mt * 16 + l16];
            #pragma unroll
            for (int nt = 0; nt < 2; ++nt) b[nt] = s_b8[kcp * 128 + wn2 + nt * 16 + l16];
            #pragma unroll
            for (int mt = 0; mt < 4; ++mt)
                #pragma unroll
                for (int nt = 0; nt < 2; ++nt)
                    acc2[mt][nt] = __builtin_amdgcn_mfma_f32_16x16x32_bf16(a[mt], b[nt], acc2[mt][nt], 0, 0, 0);
        }
    }
    __syncthreads();  // h reads done; reuse region A for proc fp32

    {
        float b2v[2];
        #pragma unroll
        for (int nt = 0; nt < 2; ++nt) b2v[nt] = b2[wn2 + nt * 16 + l16];
        #pragma unroll
        for (int mt = 0; mt < 4; ++mt)
            #pragma unroll
            for (int nt = 0; nt < 2; ++nt)
                #pragma unroll
                for (int r = 0; r < 4; ++r)
                    s_cF[(mt * 16 + q * 4 + r) * 133 + wn2 + nt * 16 + l16] = acc2[mt][nt][r] + b2v[nt];
    }
    __syncthreads();

    // Stage mw1 pack while doing LN (s_b free after GEMM2)
    {
        const char* src = (const char*)(mw1p);
        #pragma unroll
        for (int it = 0; it < 4; ++it) {
            int chunk = it * 4 + wv;
            gl_lds16(src + chunk * 1024 + lane * 16, s_b + chunk * 1024);
        }
    }

    // ---- LayerNorm over 128 cols per node; write `updated` + proc A-frags ----
    {
        const int m = t >> 2, j = t & 3;
        float vloc[32];
        float sum = 0.f, sq = 0.f;
        #pragma unroll
        for (int i = 0; i < 32; ++i) {
            float v = s_cF[m * 133 + j * 32 + i];
            vloc[i] = v; sum += v; sq += v * v;
        }
        sum += __shfl_xor(sum, 1, 4); sq += __shfl_xor(sq, 1, 4);
        sum += __shfl_xor(sum, 2, 4); sq += __shfl_xor(sq, 2, 4);
        float mu = sum * (1.f / 128.f);
        float rs = rsqrtf(sq * (1.f / 128.f) - mu * mu + 1e-5f);
        const bool wvalid = (m < nvalid);
        const int node = nodes3[m];
        float4* outp = (float4*)&out[(size_t)node * FD + j * 32];
        const float4* g4 = (const float4*)&ln_g[j * 32];
        const float4* bb4 = (const float4*)&ln_b[j * 32];
        #pragma unroll
        for (int i8 = 0; i8 < 4; ++i8) {
            unsigned short pk[8];
            #pragma unroll
            for (int h = 0; h < 2; ++h) {
                float4 g = g4[i8 * 2 + h], bb = bb4[i8 * 2 + h];
                float4 o;
                o.x = (vloc[i8 * 8 + h * 4 + 0] - mu) * rs * g.x + bb.x;
                o.y = (vloc[i8 * 8 + h * 4 + 1] - mu) * rs * g.y + bb.y;
                o.z = (vloc[i8 * 8 + h * 4 + 2] - mu) * rs * g.z + bb.z;
                o.w = (vloc[i8 * 8 + h * 4 + 3] - mu) * rs * g.w + bb.w;
                if (wvalid) outp[i8 * 2 + h] = o;
                pk[h * 4 + 0] = f2bf(o.x); pk[h * 4 + 1] = f2bf(o.y);
                pk[h * 4 + 2] = f2bf(o.z); pk[h * 4 + 3] = f2bf(o.w);
            }
            int kc = j * 4 + i8;
            *(short8*)&s_a16[PF_BYTE / 2 + (kc * 64 + m) * 8] = *(short8*)pk;
        }
    }
    __syncthreads();

    // ---- Murray head: C3[64][64] = proc[64][128] @ mw1; relu, *mw2, reduce over n ----
    {
        const int wn3 = wv * 16;
        f32x4 acc3[4];
        #pragma unroll
        for (int a = 0; a < 4; ++a) acc3[a] = (f32x4){0.f, 0.f, 0.f, 0.f};
        #pragma unroll
        for (int ks = 0; ks < 4; ++ks) {
            int kcq = ks * 4 + q;
            short8 b = s_b8[kcq * 64 + wn3 + l16];
            #pragma unroll
            for (int mt = 0; mt < 4; ++mt) {
                short8 a = s_a8[PF_BYTE / 16 + kcq * 64 + mt * 16 + l16];
                acc3[mt] = __builtin_amdgcn_mfma_f32_16x16x32_bf16(a, b, acc3[mt], 0, 0, 0);
            }
        }
        float mb1v = mb1[wn3 + l16];
        float mw2v = mw2[wn3 + l16];
        float part[16];
        #pragma unroll
        for (int mt = 0; mt < 4; ++mt)
            #pragma unroll
            for (int r = 0; r < 4; ++r) {
                float v = fmaxf(acc3[mt][r] + mb1v, 0.f) * mw2v;
                #pragma unroll
                for (int d = 1; d < 16; d <<= 1) v += __shfl_xor(v, d, 16);
                part[mt * 4 + r] = v;
            }
        if (l16 == 0) {
            #pragma unroll
            for (int mt = 0; mt < 4; ++mt)
                #pragma unroll
                for (int r = 0; r < 4; ++r)
                    red[wv * 64 + mt * 16 + q * 4 + r] = part[mt * 4 + r];
        }
    }
    __syncthreads();
    if (t < 64 && t < nvalid) {
        float v = red[t] + red[64 + t] + red[128 + t] + red[192 + t] + mb2[0];
        out[(size_t)NN * FD + nodes3[t]] = 1.f / (1.f + expf(-v));
    }
}

extern "C" void kernel_launch(void* const* d_in, const int* in_sizes, int n_in,
                              void* d_out, int out_size, void* d_ws, size_t ws_size,
                              hipStream_t stream) {
    const float* x   = (const float*)d_in[0];
    const int*   ei  = (const int*)d_in[1];
    const int* types = (const int*)d_in[2];
    const float* w1  = (const float*)d_in[3];
    const float* b1  = (const float*)d_in[4];
    const float* w2  = (const float*)d_in[5];
    const float* b2  = (const float*)d_in[6];
    const float* lg  = (const float*)d_in[7];
    const float* lb  = (const float*)d_in[8];
    const float* mw1 = (const float*)d_in[9];
    const float* mb1 = (const float*)d_in[10];
    const float* mw2 = (const float*)d_in[11];
    const float* mb2 = (const float*)d_in[12];
    float* out = (float*)d_out;
    int* ws = (int*)d_ws;

    unsigned short* w1p  = (unsigned short*)((char*)d_ws + WS_PACK_BYTES);
    unsigned short* w2p  = w1p + W1P_ELEMS;
    unsigned short* mw1p = w2p + W2P_ELEMS;

    k_init<<<(NN + 255) / 256, 256, 0, stream>>>(ws);
    k_pack<<<68, 256, 0, stream>>>(w1, w2, mw1, w1p, w2p, mw1p);
    k_min1<<<(NE + 255) / 256, 256, 0, stream>>>(ei, ws);
    k_min2<<<(NE + 255) / 256, 256, 0, stream>>>(ei, ws);
    k_compact<<<(NN + 255) / 256, 256, 0, stream>>>(types, ws, out);
    k_copy<<<(NN * FD / 4) / 256, 256, 0, stream>>>((const float4*)x, (float4*)out);
    k_mlp<<<(NN + 63) / 64, 256, 0, stream>>>(x, b1, b2, lg, lb, mb1, mw2, mb2,
                                              w1p, w2p, mw1p, ws, out);
}